// Round 7
// baseline (138.695 us; speedup 1.0000x reference)
//
#include <hip/hip_runtime.h>

#define NTOT  16384
#define NFEAT 300
#define NHID  512
#define NOUT  256
#define NACT  64
#define NEIGH 2048
#define SSZ   2112   // NACT + NEIGH
#define CSTR  64     // cols row stride
#define LCAP  160    // per-row full-row nonzero candidates (mean ~33, 22 sigma)
#define GEMMT 528    // 66 x 8 tiles of 32x64
#define K1BLK (SSZ + GEMMT + 8 + 1)   // 2649

union SM1 {
    struct {
        int scur[2304];                 // padded to 9*256
        unsigned long long smask[9][4];
        int spre[40];
        unsigned short L[LCAP];         // global-col candidates of this row
        int wtot[4];
        int snc;
    } scan;
    struct { float As[16][36]; float Bs[16][64]; } gemm;
};

// ===== K1: streaming scan (blocks <SSZ) || gemm || u=W2@iw || nb-out ========
__global__ __launch_bounds__(256) void k_front(
        const float* __restrict__ adj, const int* __restrict__ act,
        const int* __restrict__ nb,  const float* __restrict__ x,
        const float* __restrict__ W1, const float* __restrict__ W2,
        const float* __restrict__ iw,
        int* __restrict__ cnt, unsigned short* __restrict__ cols,
        float* __restrict__ B1, float* __restrict__ u,
        float* __restrict__ out)
{
    __shared__ SM1 sm;
    const int t = threadIdx.x;
    const int w = t >> 6, lane = t & 63;
    const int bid = blockIdx.x;

    if (bid < SSZ) {
        // ---- stage A: stream the full 64KB adj row, collect nonzero cols ----
        int rowid = (bid < NACT) ? act[bid] : nb[bid - NACT];
        const float4* rowv = (const float4*)(adj + (size_t)rowid * NTOT);

        for (int k = t; k < 2304; k += 256)         // scur for stage B
            sm.scan.scur[k] = (k < NACT) ? act[k] : (k < SSZ ? nb[k - NACT] : 0);

        unsigned short loc[8];
        int myc = 0;
#pragma unroll
        for (int h = 0; h < 2; ++h) {               // 2 batches of 8 float4
            float4 vv[8];
#pragma unroll
            for (int k = 0; k < 8; ++k) vv[k] = rowv[t + ((h * 8 + k) << 8)];
#pragma unroll
            for (int k = 0; k < 8; ++k) {
                int cb = (t + ((h * 8 + k) << 8)) << 2;
                if (vv[k].x != 0.0f && myc < 8) loc[myc++] = (unsigned short)cb;
                if (vv[k].y != 0.0f && myc < 8) loc[myc++] = (unsigned short)(cb + 1);
                if (vv[k].z != 0.0f && myc < 8) loc[myc++] = (unsigned short)(cb + 2);
                if (vv[k].w != 0.0f && myc < 8) loc[myc++] = (unsigned short)(cb + 3);
            }
        }
        // deterministic compaction into L: wave shfl-scan + cross-wave offsets
        int iv = myc;
#pragma unroll
        for (int o = 1; o < 64; o <<= 1) {
            int xx = __shfl_up(iv, o, 64);
            if (lane >= o) iv += xx;
        }
        if (lane == 63) sm.scan.wtot[w] = iv;
        __syncthreads();
        int base = 0;
        for (int i = 0; i < w; ++i) base += sm.scan.wtot[i];
        int off = base + iv - myc;
        for (int i = 0; i < myc; ++i)
            if (off + i < LCAP) sm.scan.L[off + i] = loc[i];
        if (t == 255) sm.scan.snc = min(off + myc, LCAP);
        __syncthreads();

        // ---- stage B: hit[j] = (scur[j] in L), then ballot compaction ------
        const int snc = sm.scan.snc;
        int scurj[9];
#pragma unroll
        for (int k = 0; k < 9; ++k) scurj[k] = sm.scan.scur[t + (k << 8)];
        bool hit[9] = {false,false,false,false,false,false,false,false,false};
        for (int i = 0; i < snc; ++i) {
            int ci = sm.scan.L[i];
#pragma unroll
            for (int k = 0; k < 9; ++k) hit[k] |= (scurj[k] == ci);
        }
#pragma unroll
        for (int k = 0; k < 9; ++k) {
            int j = t + (k << 8);
            hit[k] = hit[k] && (j < SSZ);
            unsigned long long m = __ballot(hit[k]);
            if (lane == 0) sm.scan.smask[k][w] = m;
        }
        __syncthreads();
        if (t < 64) {                                // prefix over 36 groups
            int c = (t < 36) ? __popcll(sm.scan.smask[t >> 2][t & 3]) : 0;
            int vv = c;
#pragma unroll
            for (int o = 1; o < 64; o <<= 1) {
                int xx = __shfl_up(vv, o, 64);
                if (lane >= o) vv += xx;
            }
            if (t == 0) sm.scan.spre[0] = 0;
            if (t < 36) sm.scan.spre[t + 1] = vv;
        }
        __syncthreads();
        unsigned short* dst = cols + (size_t)bid * CSTR;
#pragma unroll
        for (int k = 0; k < 9; ++k) {
            if (hit[k]) {
                unsigned long long below = sm.scan.smask[k][w] & ((1ull << lane) - 1ull);
                dst[sm.scan.spre[k * 4 + w] + __popcll(below)] =
                    (unsigned short)(t + (k << 8));
            }
        }
        if (t == 0) cnt[bid] = sm.scan.spre[36];
    } else if (bid < SSZ + GEMMT) {
        // ---------------- GEMM tile 32x64 of X[cur] @ W1 --------------------
        int it = bid - SSZ;
        int bm = (it % 66) * 32, bn = (it / 66) * 64;
        int tx = t & 15, ty = t >> 4;
        float acc[2][4] = {};
        for (int kt = 0; kt < NFEAT; kt += 16) {
#pragma unroll
            for (int l = 0; l < 2; ++l) {
                int idx = t + l * 256;
                int m = idx >> 4, kk = idx & 15;
                int gk = kt + kk, gm = bm + m;
                int ar = (gm < NACT) ? act[gm] : nb[gm - NACT];
                sm.gemm.As[kk][m] = (gk < NFEAT) ? x[(size_t)ar * NFEAT + gk] : 0.0f;
            }
#pragma unroll
            for (int l = 0; l < 4; ++l) {
                int idx = t + l * 256;
                int nn = idx & 63, kk = idx >> 6;
                int gk = kt + kk;
                sm.gemm.Bs[kk][nn] = (gk < NFEAT) ? W1[(size_t)gk * NHID + bn + nn] : 0.0f;
            }
            __syncthreads();
#pragma unroll
            for (int kk = 0; kk < 16; ++kk) {
                float a0 = sm.gemm.As[kk][ty * 2], a1 = sm.gemm.As[kk][ty * 2 + 1];
                float4 bv = *(const float4*)&sm.gemm.Bs[kk][tx * 4];
                acc[0][0] += a0 * bv.x; acc[0][1] += a0 * bv.y;
                acc[0][2] += a0 * bv.z; acc[0][3] += a0 * bv.w;
                acc[1][0] += a1 * bv.x; acc[1][1] += a1 * bv.y;
                acc[1][2] += a1 * bv.z; acc[1][3] += a1 * bv.w;
            }
            __syncthreads();
        }
#pragma unroll
        for (int r = 0; r < 2; ++r) {
            int gm = bm + ty * 2 + r;
            *(float4*)&B1[(size_t)gm * NHID + bn + tx * 4] =
                make_float4(acc[r][0], acc[r][1], acc[r][2], acc[r][3]);
        }
    } else if (bid < SSZ + GEMMT + 8) {
        // ---------------- u = W2 @ imp_w, 64 rows per block ------------------
        int r0 = (bid - SSZ - GEMMT) * 64;
        for (int r = r0 + w; r < r0 + 64; r += 4) {
            float p = 0.0f;
#pragma unroll
            for (int q = 0; q < 4; ++q)
                p += W2[(size_t)r * NOUT + lane + q * 64] * iw[lane + q * 64];
#pragma unroll
            for (int o = 32; o > 0; o >>= 1) p += __shfl_down(p, o, 64);
            if (lane == 0) u[r] = p;
        }
    } else {
        // ---------------- neighbor ids -> out tail ---------------------------
        for (int i = t; i < NEIGH; i += 256) out[NEIGH + i] = (float)nb[i];
    }
}

// ===== K2: fused relu-spMV, one block per row ================================
__global__ __launch_bounds__(256) void k_spmv(const float* __restrict__ B1,
                                              const int* __restrict__ cnt,
                                              const unsigned short* __restrict__ cols,
                                              const float* __restrict__ u,
                                              float* __restrict__ v) {
    __shared__ float su[NHID];
    __shared__ float wsum[4];
    int t = threadIdx.x, row = blockIdx.x;
    su[t] = u[t]; su[t + 256] = u[t + 256];

    int n = cnt[row];
    const unsigned short* cl = cols + (size_t)row * CSTR;
    float a0 = 0.0f, a1 = 0.0f;
    for (int k = 0; k < n; ++k) {
        int j = cl[k];
        a0 += B1[(size_t)j * NHID + t];
        a1 += B1[(size_t)j * NHID + t + 256];
    }
    __syncthreads();
    float p = fmaxf(a0, 0.0f) * su[t] + fmaxf(a1, 0.0f) * su[t + 256];
#pragma unroll
    for (int o = 32; o > 0; o >>= 1) p += __shfl_down(p, o, 64);
    if ((t & 63) == 0) wsum[t >> 6] = p;
    __syncthreads();
    if (t == 0) v[row] = wsum[0] + wsum[1] + wsum[2] + wsum[3];
}

// ===== K3: final, single block x 1024 =======================================
__global__ __launch_bounds__(1024) void k_final(const int* __restrict__ cnt,
                                                const unsigned short* __restrict__ cols,
                                                const float* __restrict__ v,
                                                const float* __restrict__ ib,
                                                float* __restrict__ out) {
    __shared__ float sv[SSZ];
    __shared__ float s1[SSZ];
    __shared__ float s2[SSZ];
    __shared__ int   sc[SSZ];
    __shared__ float wsum[16];
    __shared__ float inv;
    int t = threadIdx.x;
    for (int i = t; i < SSZ; i += 1024) { sv[i] = v[i]; sc[i] = cnt[i]; }
    __syncthreads();
    for (int i = t; i < SSZ; i += 1024) {
        const unsigned short* cl = cols + (size_t)i * CSTR;
        int n = sc[i];
        float s = 0.0f;
        for (int k = 0; k < n; ++k) s += sv[cl[k]];
        s1[i] = s;
    }
    __syncthreads();
    float bias = ib[0];
    for (int i = t; i < SSZ; i += 1024) {
        const unsigned short* cl = cols + (size_t)i * CSTR;
        int n = sc[i];
        float s = 0.0f;
        for (int k = 0; k < n; ++k) s += s1[cl[k]];
        s2[i] = s + bias;
    }
    __syncthreads();
    float s = 0.0f;
    for (int i = t; i < SSZ; i += 1024) s += fabsf(s2[i]);
#pragma unroll
    for (int o = 32; o > 0; o >>= 1) s += __shfl_down(s, o, 64);
    if ((t & 63) == 0) wsum[t >> 6] = s;
    __syncthreads();
    if (t == 0) {
        float tot = 0.0f;
#pragma unroll
        for (int k = 0; k < 16; ++k) tot += wsum[k];
        inv = 1.0f / fmaxf(tot, 1e-12f);
    }
    __syncthreads();
    for (int i = t; i < NEIGH; i += 1024) out[i] = s2[NACT + i] * inv;
}

// --------------------------------------------------------------------------
extern "C" void kernel_launch(void* const* d_in, const int* in_sizes, int n_in,
                              void* d_out, int out_size, void* d_ws, size_t ws_size,
                              hipStream_t stream) {
    const float* x   = (const float*)d_in[0];
    const float* adj = (const float*)d_in[1];
    const int*   act = (const int*)d_in[2];
    const int*   nb  = (const int*)d_in[3];
    const float* W1  = (const float*)d_in[4];
    const float* W2  = (const float*)d_in[5];
    const float* iw  = (const float*)d_in[6];
    const float* ib  = (const float*)d_in[7];
    float* out = (float*)d_out;

    // workspace layout (bytes) — total ~4.62 MB
    char* ws = (char*)d_ws;
    int*            cnt  = (int*)           (ws + 0);        // 8448 B
    unsigned short* cols = (unsigned short*)(ws + 8704);     // 270336 B
    float*          B1   = (float*)         (ws + 279040);   // 4.33 MB
    float*          u    = (float*)         (ws + 4604416);  // 2 KB
    float*          v    = (float*)         (ws + 4606464);  // 8448 B

    k_front<<<dim3(K1BLK), 256,  0, stream>>>(adj, act, nb, x, W1, W2, iw,
                                              cnt, cols, B1, u, out);
    k_spmv <<<dim3(SSZ),   256,  0, stream>>>(B1, cnt, cols, u, v);
    k_final<<<dim3(1),     1024, 0, stream>>>(cnt, cols, v, ib, out);
}

// Round 8
// 97.994 us; speedup vs baseline: 1.4154x; 1.4154x over previous
//
#include <hip/hip_runtime.h>

#define NTOT  16384
#define NFEAT 300
#define NHID  512
#define NOUT  256
#define NACT  64
#define NEIGH 2048
#define SSZ   2112   // NACT + NEIGH
#define CSTR  64     // cols row stride
#define GEMMT 528    // 66 x 8 tiles of 32x64
#define K1BLK (GEMMT + SSZ + 8 + 1)   // 2649

union SM1 {
    struct {
        int scur[2304];                 // padded to 9*256
        unsigned int bm[512];           // 16384-bit nonzero-column bitmap
        unsigned long long smask[9][4];
        int spre[40];
    } scan;
    struct { float As[16][36]; float Bs[16][64]; } gemm;
};

// ===== K1: gemm (bid<GEMMT) || stream-scan || u=W2@iw || nb-out =============
__global__ __launch_bounds__(256) void k_front(
        const float* __restrict__ adj, const int* __restrict__ act,
        const int* __restrict__ nb,  const float* __restrict__ x,
        const float* __restrict__ W1, const float* __restrict__ W2,
        const float* __restrict__ iw,
        int* __restrict__ cnt, unsigned short* __restrict__ cols,
        float* __restrict__ B1, float* __restrict__ u,
        float* __restrict__ out)
{
    __shared__ SM1 sm;
    const int t = threadIdx.x;
    const int w = t >> 6, lane = t & 63;
    const int bid = blockIdx.x;

    if (bid < GEMMT) {
        // ---------------- GEMM tile 32x64 of X[cur] @ W1 --------------------
        int it = bid;
        int bm_ = (it % 66) * 32, bn = (it / 66) * 64;
        int tx = t & 15, ty = t >> 4;
        float acc[2][4] = {};
        for (int kt = 0; kt < NFEAT; kt += 16) {
#pragma unroll
            for (int l = 0; l < 2; ++l) {
                int idx = t + l * 256;
                int m = idx >> 4, kk = idx & 15;
                int gk = kt + kk, gm = bm_ + m;
                int ar = (gm < NACT) ? act[gm] : nb[gm - NACT];
                sm.gemm.As[kk][m] = (gk < NFEAT) ? x[(size_t)ar * NFEAT + gk] : 0.0f;
            }
#pragma unroll
            for (int l = 0; l < 4; ++l) {
                int idx = t + l * 256;
                int nn = idx & 63, kk = idx >> 6;
                int gk = kt + kk;
                sm.gemm.Bs[kk][nn] = (gk < NFEAT) ? W1[(size_t)gk * NHID + bn + nn] : 0.0f;
            }
            __syncthreads();
#pragma unroll
            for (int kk = 0; kk < 16; ++kk) {
                float a0 = sm.gemm.As[kk][ty * 2], a1 = sm.gemm.As[kk][ty * 2 + 1];
                float4 bv = *(const float4*)&sm.gemm.Bs[kk][tx * 4];
                acc[0][0] += a0 * bv.x; acc[0][1] += a0 * bv.y;
                acc[0][2] += a0 * bv.z; acc[0][3] += a0 * bv.w;
                acc[1][0] += a1 * bv.x; acc[1][1] += a1 * bv.y;
                acc[1][2] += a1 * bv.z; acc[1][3] += a1 * bv.w;
            }
            __syncthreads();
        }
#pragma unroll
        for (int r = 0; r < 2; ++r) {
            int gm = bm_ + ty * 2 + r;
            *(float4*)&B1[(size_t)gm * NHID + bn + tx * 4] =
                make_float4(acc[r][0], acc[r][1], acc[r][2], acc[r][3]);
        }
    } else if (bid < GEMMT + SSZ) {
        // ---- stream-scan: full-row read + LDS bitmap + ballot compaction ----
        const int row = bid - GEMMT;
        int rowid = (row < NACT) ? act[row] : nb[row - NACT];
        const float4* rowv = (const float4*)(adj + (size_t)rowid * NTOT);

        float4 vv[16];                           // 64KB row: 16 float4/thread
#pragma unroll
        for (int k = 0; k < 16; ++k) vv[k] = rowv[t + (k << 8)];

        for (int k = t; k < 2304; k += 256)
            sm.scan.scur[k] = (k < NACT) ? act[k] : (k < SSZ ? nb[k - NACT] : 0);
        for (int k = t; k < 512; k += 256) sm.scan.bm[k] = 0;
        __syncthreads();

#pragma unroll
        for (int k = 0; k < 16; ++k) {           // ~33 rare atomicOr per block
            int cb = (t + (k << 8)) << 2;        // cb..cb+3 share one bm word
            unsigned int m = 0;
            if (vv[k].x != 0.0f) m |= 1u << ((cb + 0) & 31);
            if (vv[k].y != 0.0f) m |= 1u << ((cb + 1) & 31);
            if (vv[k].z != 0.0f) m |= 1u << ((cb + 2) & 31);
            if (vv[k].w != 0.0f) m |= 1u << ((cb + 3) & 31);
            if (m) atomicOr(&sm.scan.bm[cb >> 5], m);
        }
        __syncthreads();

        bool hit[9];
#pragma unroll
        for (int k = 0; k < 9; ++k) {            // 9 independent LDS lookups
            int j = t + (k << 8);
            int c = sm.scan.scur[j];
            hit[k] = (j < SSZ) && ((sm.scan.bm[c >> 5] >> (c & 31)) & 1u);
            unsigned long long m = __ballot(hit[k]);
            if (lane == 0) sm.scan.smask[k][w] = m;
        }
        __syncthreads();
        if (t < 64) {                            // prefix over 36 groups
            int c = (t < 36) ? __popcll(sm.scan.smask[t >> 2][t & 3]) : 0;
            int vvp = c;
#pragma unroll
            for (int o = 1; o < 64; o <<= 1) {
                int xx = __shfl_up(vvp, o, 64);
                if (lane >= o) vvp += xx;
            }
            if (t == 0) sm.scan.spre[0] = 0;
            if (t < 36) sm.scan.spre[t + 1] = vvp;
        }
        __syncthreads();
        unsigned short* dst = cols + (size_t)row * CSTR;
#pragma unroll
        for (int k = 0; k < 9; ++k) {
            if (hit[k]) {
                unsigned long long below = sm.scan.smask[k][w] & ((1ull << lane) - 1ull);
                dst[sm.scan.spre[k * 4 + w] + __popcll(below)] =
                    (unsigned short)(t + (k << 8));
            }
        }
        if (t == 0) cnt[row] = sm.scan.spre[36];
    } else if (bid < GEMMT + SSZ + 8) {
        // ---------------- u = W2 @ imp_w, 64 rows per block ------------------
        int r0 = (bid - GEMMT - SSZ) * 64;
        for (int r = r0 + w; r < r0 + 64; r += 4) {
            float p = 0.0f;
#pragma unroll
            for (int q = 0; q < 4; ++q)
                p += W2[(size_t)r * NOUT + lane + q * 64] * iw[lane + q * 64];
#pragma unroll
            for (int o = 32; o > 0; o >>= 1) p += __shfl_down(p, o, 64);
            if (lane == 0) u[r] = p;
        }
    } else {
        // ---------------- neighbor ids -> out tail ---------------------------
        for (int i = t; i < NEIGH; i += 256) out[NEIGH + i] = (float)nb[i];
    }
}

// ===== K2: fused relu-spMV, one block per row ================================
__global__ __launch_bounds__(256) void k_spmv(const float* __restrict__ B1,
                                              const int* __restrict__ cnt,
                                              const unsigned short* __restrict__ cols,
                                              const float* __restrict__ u,
                                              float* __restrict__ v) {
    __shared__ float su[NHID];
    __shared__ float wsum[4];
    int t = threadIdx.x, row = blockIdx.x;
    su[t] = u[t]; su[t + 256] = u[t + 256];

    int n = cnt[row];
    const unsigned short* cl = cols + (size_t)row * CSTR;
    float a0 = 0.0f, a1 = 0.0f;
    for (int k = 0; k < n; ++k) {
        int j = cl[k];
        a0 += B1[(size_t)j * NHID + t];
        a1 += B1[(size_t)j * NHID + t + 256];
    }
    __syncthreads();
    float p = fmaxf(a0, 0.0f) * su[t] + fmaxf(a1, 0.0f) * su[t + 256];
#pragma unroll
    for (int o = 32; o > 0; o >>= 1) p += __shfl_down(p, o, 64);
    if ((t & 63) == 0) wsum[t >> 6] = p;
    __syncthreads();
    if (t == 0) v[row] = wsum[0] + wsum[1] + wsum[2] + wsum[3];
}

// ===== K3: final, single block x 1024 =======================================
__global__ __launch_bounds__(1024) void k_final(const int* __restrict__ cnt,
                                                const unsigned short* __restrict__ cols,
                                                const float* __restrict__ v,
                                                const float* __restrict__ ib,
                                                float* __restrict__ out) {
    __shared__ float sv[SSZ];
    __shared__ float s1[SSZ];
    __shared__ float s2[SSZ];
    __shared__ int   sc[SSZ];
    __shared__ float wsum[16];
    __shared__ float inv;
    int t = threadIdx.x;
    for (int i = t; i < SSZ; i += 1024) { sv[i] = v[i]; sc[i] = cnt[i]; }
    __syncthreads();
    for (int i = t; i < SSZ; i += 1024) {
        const unsigned short* cl = cols + (size_t)i * CSTR;
        int n = sc[i];
        float s = 0.0f;
        for (int k = 0; k < n; ++k) s += sv[cl[k]];
        s1[i] = s;
    }
    __syncthreads();
    float bias = ib[0];
    for (int i = t; i < SSZ; i += 1024) {
        const unsigned short* cl = cols + (size_t)i * CSTR;
        int n = sc[i];
        float s = 0.0f;
        for (int k = 0; k < n; ++k) s += s1[cl[k]];
        s2[i] = s + bias;
    }
    __syncthreads();
    float s = 0.0f;
    for (int i = t; i < SSZ; i += 1024) s += fabsf(s2[i]);
#pragma unroll
    for (int o = 32; o > 0; o >>= 1) s += __shfl_down(s, o, 64);
    if ((t & 63) == 0) wsum[t >> 6] = s;
    __syncthreads();
    if (t == 0) {
        float tot = 0.0f;
#pragma unroll
        for (int k = 0; k < 16; ++k) tot += wsum[k];
        inv = 1.0f / fmaxf(tot, 1e-12f);
    }
    __syncthreads();
    for (int i = t; i < NEIGH; i += 1024) out[i] = s2[NACT + i] * inv;
}

// --------------------------------------------------------------------------
extern "C" void kernel_launch(void* const* d_in, const int* in_sizes, int n_in,
                              void* d_out, int out_size, void* d_ws, size_t ws_size,
                              hipStream_t stream) {
    const float* x   = (const float*)d_in[0];
    const float* adj = (const float*)d_in[1];
    const int*   act = (const int*)d_in[2];
    const int*   nb  = (const int*)d_in[3];
    const float* W1  = (const float*)d_in[4];
    const float* W2  = (const float*)d_in[5];
    const float* iw  = (const float*)d_in[6];
    const float* ib  = (const float*)d_in[7];
    float* out = (float*)d_out;

    // workspace layout (bytes) — total ~4.62 MB
    char* ws = (char*)d_ws;
    int*            cnt  = (int*)           (ws + 0);        // 8448 B
    unsigned short* cols = (unsigned short*)(ws + 8704);     // 270336 B
    float*          B1   = (float*)         (ws + 279040);   // 4.33 MB
    float*          u    = (float*)         (ws + 4604416);  // 2 KB
    float*          v    = (float*)         (ws + 4606464);  // 8448 B

    k_front<<<dim3(K1BLK), 256,  0, stream>>>(adj, act, nb, x, W1, W2, iw,
                                              cnt, cols, B1, u, out);
    k_spmv <<<dim3(SSZ),   256,  0, stream>>>(B1, cnt, cols, u, v);
    k_final<<<dim3(1),     1024, 0, stream>>>(cnt, cols, v, ib, out);
}